// Round 13
// baseline (486.338 us; speedup 1.0000x reference)
//
#include <hip/hip_runtime.h>
#include <hip/hip_bf16.h>

#define DIM   1536
#define HEADS 12
#define HD    128
#define SEQ   4096
#define QSCALE 0.08838834764831845f
#define LOG2E 1.44269504088896f

typedef __attribute__((ext_vector_type(8))) short short8;
typedef __attribute__((ext_vector_type(4))) float f32x4;

__device__ __forceinline__ unsigned short f2bf(float f) {
    __hip_bfloat16 h = __float2bfloat16(f);
    return *reinterpret_cast<unsigned short*>(&h);
}
__device__ __forceinline__ float bf2f(unsigned short u) {
    return __uint_as_float(((unsigned int)u) << 16);
}
__device__ __forceinline__ void async_cp16(void* lds, const void* g) {
    __builtin_amdgcn_global_load_lds(
        (const __attribute__((address_space(1))) unsigned int*)g,
        (__attribute__((address_space(3))) unsigned int*)lds, 16, 0, 0);
}

// ---------------------------------------------------------------------------
// GEMM: y = x @ W^T + b, fused QKV via blockIdx.z. (unchanged, verified)
// ---------------------------------------------------------------------------
__global__ __launch_bounds__(256) void gemm_qkv(
    const float* __restrict__ x,
    const float* __restrict__ wq, const float* __restrict__ bq,
    const float* __restrict__ wk, const float* __restrict__ bk,
    const float* __restrict__ wv, const float* __restrict__ bv,
    __hip_bfloat16* __restrict__ yq, __hip_bfloat16* __restrict__ yk,
    __hip_bfloat16* __restrict__ vrow)
{
    __shared__ __align__(16) short As[128][40];
    __shared__ __align__(16) short Bs[128][40];
    const int z  = blockIdx.z;
    const float* W    = (z == 0) ? wq : (z == 1) ? wk : wv;
    const float* bias = (z == 0) ? bq : (z == 1) ? bk : bv;
    __hip_bfloat16* outp = (z == 0) ? yq : (z == 1) ? yk : vrow;
    const int bm0 = blockIdx.x * 128;
    const int bn0 = blockIdx.y * 128;
    const int tid  = threadIdx.x;
    const int lane = tid & 63;
    const int wid  = tid >> 6;
    const int wm = (wid >> 1) * 64;
    const int wn = (wid & 1)  * 64;
    const int fr = lane & 15;
    const int fc = (lane >> 4) * 8;
    const int srow = tid >> 3;
    const int scol = (tid & 7) * 4;

    f32x4 acc[4][4] = {};

    for (int kt = 0; kt < DIM; kt += 32) {
        #pragma unroll
        for (int p = 0; p < 4; ++p) {
            const int r = srow + p * 32;
            float4 va = *reinterpret_cast<const float4*>(&x[(size_t)(bm0 + r) * DIM + kt + scol]);
            float4 vb = *reinterpret_cast<const float4*>(&W[(size_t)(bn0 + r) * DIM + kt + scol]);
            uint2 pa, pb;
            pa.x = (unsigned int)f2bf(va.x) | ((unsigned int)f2bf(va.y) << 16);
            pa.y = (unsigned int)f2bf(va.z) | ((unsigned int)f2bf(va.w) << 16);
            pb.x = (unsigned int)f2bf(vb.x) | ((unsigned int)f2bf(vb.y) << 16);
            pb.y = (unsigned int)f2bf(vb.z) | ((unsigned int)f2bf(vb.w) << 16);
            *reinterpret_cast<uint2*>(&As[r][scol]) = pa;
            *reinterpret_cast<uint2*>(&Bs[r][scol]) = pb;
        }
        __syncthreads();
        short8 af[4], bf8[4];
        #pragma unroll
        for (int m = 0; m < 4; m++) af[m]  = *reinterpret_cast<const short8*>(&As[wm + m * 16 + fr][fc]);
        #pragma unroll
        for (int n = 0; n < 4; n++) bf8[n] = *reinterpret_cast<const short8*>(&Bs[wn + n * 16 + fr][fc]);
        #pragma unroll
        for (int m = 0; m < 4; m++)
            #pragma unroll
            for (int n = 0; n < 4; n++)
                acc[m][n] = __builtin_amdgcn_mfma_f32_16x16x32_bf16(af[m], bf8[n], acc[m][n], 0, 0, 0);
        __syncthreads();
    }

    const int crow0 = bm0 + wm + (lane >> 4) * 4;
    const int ccol0 = bn0 + wn + fr;
    #pragma unroll
    for (int n = 0; n < 4; n++) {
        const int col = ccol0 + n * 16;
        const float bb = bias[col];
        #pragma unroll
        for (int m = 0; m < 4; m++)
            #pragma unroll
            for (int r = 0; r < 4; r++)
                outp[(size_t)(crow0 + m * 16 + r) * DIM + col] =
                    __float2bfloat16(acc[m][n][r] + bb);
    }
}

// ---------------------------------------------------------------------------
// In-place RMSNorm * g + RoPE. (unchanged, verified)
// ---------------------------------------------------------------------------
__global__ __launch_bounds__(256) void rmsnorm_rope(
    __hip_bfloat16* __restrict__ yq, __hip_bfloat16* __restrict__ yk,
    const float* __restrict__ gq, const float* __restrict__ gk,
    const float* __restrict__ freqs)
{
    const int s = blockIdx.x;
    const int z = blockIdx.y;
    __hip_bfloat16* y = z ? yk : yq;
    const float* g = z ? gk : gq;
    const int t = threadIdx.x;

    float xr[3], xi[3];
    float ss = 0.f;
    #pragma unroll
    for (int i = 0; i < 3; i++) {
        const int p = t + i * 256;
        const unsigned int uu = *reinterpret_cast<const unsigned int*>(&y[(size_t)s * DIM + 2 * p]);
        xr[i] = bf2f((unsigned short)(uu & 0xffffu));
        xi[i] = bf2f((unsigned short)(uu >> 16));
        ss += xr[i] * xr[i] + xi[i] * xi[i];
    }
    #pragma unroll
    for (int m = 1; m < 64; m <<= 1) ss += __shfl_xor(ss, m, 64);
    __shared__ float red[4];
    if ((t & 63) == 0) red[t >> 6] = ss;
    __syncthreads();
    const float sum = red[0] + red[1] + red[2] + red[3];
    const float rs = rsqrtf(sum * (1.0f / DIM) + 1e-6f);
    const int f = s >> 8, hh = (s >> 4) & 15, ww = s & 15;
    const float osc = z ? 1.0f : QSCALE;
    #pragma unroll
    for (int i = 0; i < 3; i++) {
        const int p = t + i * 256;
        const int cc = p & 63;
        const int pos = (cc < 22) ? f : (cc < 43) ? hh : ww;
        const float ang = freqs[pos * 64 + cc];
        float sn, cs;
        sincosf(ang, &sn, &cs);
        const float a = xr[i] * rs * g[2 * p];
        const float b = xi[i] * rs * g[2 * p + 1];
        const unsigned int pk = (unsigned int)f2bf((a * cs - b * sn) * osc)
                              | ((unsigned int)f2bf((a * sn + b * cs) * osc) << 16);
        *reinterpret_cast<unsigned int*>(&y[(size_t)s * DIM + 2 * p]) = pk;
    }
}

// ---------------------------------------------------------------------------
// Transpose V. (unchanged, verified)
// ---------------------------------------------------------------------------
__global__ __launch_bounds__(256) void transpose_v(
    const __hip_bfloat16* __restrict__ vrow,
    __hip_bfloat16* __restrict__ vT)
{
    __shared__ __align__(16) short tile[64][72];
    const int s0 = blockIdx.x * 64;
    const int c0 = blockIdx.y * 64;
    const int t = threadIdx.x;
    #pragma unroll
    for (int i = 0; i < 2; i++) {
        const int ch = t + i * 256;
        const int r = ch >> 3, cc = (ch & 7) * 8;
        *reinterpret_cast<int4*>(&tile[r][cc]) =
            *reinterpret_cast<const int4*>(&vrow[(size_t)(s0 + r) * DIM + c0 + cc]);
    }
    __syncthreads();
    #pragma unroll
    for (int i = 0; i < 2; i++) {
        const int ch = t + i * 256;
        const int c = ch & 63, sc = (ch >> 6) * 8;
        unsigned int w0 = (unsigned short)tile[sc + 0][c] | ((unsigned int)(unsigned short)tile[sc + 1][c] << 16);
        unsigned int w1 = (unsigned short)tile[sc + 2][c] | ((unsigned int)(unsigned short)tile[sc + 3][c] << 16);
        unsigned int w2 = (unsigned short)tile[sc + 4][c] | ((unsigned int)(unsigned short)tile[sc + 5][c] << 16);
        unsigned int w3 = (unsigned short)tile[sc + 6][c] | ((unsigned int)(unsigned short)tile[sc + 7][c] << 16);
        int4 val;
        val.x = (int)w0; val.y = (int)w1; val.z = (int)w2; val.w = (int)w3;
        *reinterpret_cast<int4*>(&vT[(size_t)(c0 + c) * SEQ + s0 + sc]) = val;
    }
}

// ---------------------------------------------------------------------------
// Flash attention v6: v5 pipeline skeleton (gload_lds dbuf + swizzle) with
// O^T PV (mfma(V^T, P): alpha/l lane-local), defer-max (T13), uniform
// full-tile mask fast path, packed 8B output stores.
// ---------------------------------------------------------------------------
__global__ __launch_bounds__(256) void flash_attn(
    const __hip_bfloat16* __restrict__ qb,
    const __hip_bfloat16* __restrict__ kb,
    const __hip_bfloat16* __restrict__ vT,
    const int* __restrict__ seq_lens,
    __hip_bfloat16* __restrict__ attno)
{
    __shared__ __align__(16) short Ks[2][64][128];   // 2 x 16 KB, linear
    __shared__ __align__(16) short Vs[2][128][64];   // 2 x 16 KB, linear
    const int qt = blockIdx.x;
    const int h  = blockIdx.y;
    const int tid = threadIdx.x;
    const int lane = tid & 63;
    const int w = tid >> 6;
    const int fr = lane & 15;
    const int fg = lane >> 4;       // 0..3
    const int seqlen = seq_lens[0];
    const int sw = (fr & 7) << 4;   // read-side XOR swizzle (bytes)

    // Q fragments (B-operand of swapped QK^T): rows = q (fr), k-slice = fg*8
    short8 qf[4];
    const int qrow = qt * 64 + w * 16 + fr;
    #pragma unroll
    for (int kc = 0; kc < 4; kc++)
        qf[kc] = *reinterpret_cast<const short8*>(&qb[(size_t)qrow * DIM + h * HD + kc * 32 + fg * 8]);

    f32x4 oacc[8] = {};          // O^T: oacc[n][r] = chan n*16+fg*4+r, q = fr
    float m = -1e30f, l = 0.f;   // softmax state for q-row = fr (lane-local)

    const int kROW = w * 4 + (lane >> 4);            // + i*16
    const int kCOL = ((lane & 15) ^ (kROW & 7)) * 8; // pre-swizzled source col
    const int vROW = w * 8 + (lane >> 3);            // + i*32
    const int vCOL = (((lane & 7) ^ (vROW & 7))) * 8;

    // prologue: stage tile 0 into buffer 0
    #pragma unroll
    for (int i = 0; i < 4; i++) {
        async_cp16(&Ks[0][i * 16 + w * 4][0],
                   kb + (size_t)(i * 16 + kROW) * DIM + h * HD + kCOL);
        async_cp16(&Vs[0][i * 32 + w * 8][0],
                   vT + ((size_t)h * HD + i * 32 + vROW) * SEQ + vCOL);
    }
    __syncthreads();

    for (int t = 0; t < SEQ / 64; t++) {
        const int cur = t & 1;
        const int kbase = t * 64;
        // issue next tile's async loads first; latency hides under compute
        if (t + 1 < SEQ / 64) {
            const int nb = kbase + 64;
            #pragma unroll
            for (int i = 0; i < 4; i++) {
                async_cp16(&Ks[cur ^ 1][i * 16 + w * 4][0],
                           kb + (size_t)(nb + i * 16 + kROW) * DIM + h * HD + kCOL);
                async_cp16(&Vs[cur ^ 1][i * 32 + w * 8][0],
                           vT + ((size_t)h * HD + i * 32 + vROW) * SEQ + nb + vCOL);
            }
        }
        const char* Kp = (const char*)&Ks[cur][0][0];
        const char* Vp = (const char*)&Vs[cur][0][0];

        // S^T = K Q^T : lane holds keys n*16 + fg*4 + r for q-row fr
        f32x4 sacc[4] = {};
        __builtin_amdgcn_s_setprio(1);
        #pragma unroll
        for (int kc = 0; kc < 4; kc++) {
            #pragma unroll
            for (int n = 0; n < 4; n++) {
                short8 kf = *reinterpret_cast<const short8*>(
                    Kp + (n * 16 + fr) * 256 + ((kc * 64 + fg * 16) ^ sw));
                sacc[n] = __builtin_amdgcn_mfma_f32_16x16x32_bf16(kf, qf[kc], sacc[n], 0, 0, 0);
            }
        }
        __builtin_amdgcn_s_setprio(0);

        // row max (uniform fast path when tile fully valid)
        float tmax = -1e30f;
        if (kbase + 64 <= seqlen) {
            #pragma unroll
            for (int n = 0; n < 4; n++)
                #pragma unroll
                for (int r = 0; r < 4; r++) tmax = fmaxf(tmax, sacc[n][r]);
        } else {
            #pragma unroll
            for (int n = 0; n < 4; n++) {
                #pragma unroll
                for (int r = 0; r < 4; r++) {
                    const int key = kbase + n * 16 + fg * 4 + r;
                    const float sv = (key < seqlen) ? sacc[n][r] : -1e30f;
                    sacc[n][r] = sv;
                    tmax = fmaxf(tmax, sv);
                }
            }
        }
        tmax = fmaxf(tmax, __shfl_xor(tmax, 16, 64));
        tmax = fmaxf(tmax, __shfl_xor(tmax, 32, 64));

        // defer-max (T13): rescale only when some row grew past THR=8
        if (!__all(tmax <= m + 8.0f)) {
            const float mn = fmaxf(m, tmax);
            const float alpha = exp2f((m - mn) * LOG2E);
            m = mn;
            l *= alpha;
            #pragma unroll
            for (int n = 0; n < 8; n++)
                #pragma unroll
                for (int r = 0; r < 4; r++) oacc[n][r] *= alpha;
        }

        // P = exp(S - m); row sum (lane-local q = fr)
        float ps = 0.f;
        #pragma unroll
        for (int n = 0; n < 4; n++) {
            #pragma unroll
            for (int r = 0; r < 4; r++) {
                const float p = exp2f((sacc[n][r] - m) * LOG2E);
                sacc[n][r] = p;
                ps += p;
            }
        }
        ps += __shfl_xor(ps, 16, 64);
        ps += __shfl_xor(ps, 32, 64);
        l += ps;

        unsigned int pk[4][2];
        #pragma unroll
        for (int n = 0; n < 4; n++) {
            pk[n][0] = (unsigned int)f2bf(sacc[n][0]) | ((unsigned int)f2bf(sacc[n][1]) << 16);
            pk[n][1] = (unsigned int)f2bf(sacc[n][2]) | ((unsigned int)f2bf(sacc[n][3]) << 16);
        }

        // O^T += V^T P : pf gathered by shuffle (P[q=fr][keys kc*32+fg*8..+8])
        const int aSel = fg >> 1;
        const int h0 = fr + 32 * (fg & 1);
        const int h1 = h0 + 16;
        #pragma unroll
        for (int kc = 0; kc < 2; kc++) {
            const unsigned int e00 = (unsigned int)__shfl((int)pk[2 * kc][0], h0, 64);
            const unsigned int e01 = (unsigned int)__shfl((int)pk[2 * kc][1], h0, 64);
            const unsigned int e02 = (unsigned int)__shfl((int)pk[2 * kc][0], h1, 64);
            const unsigned int e03 = (unsigned int)__shfl((int)pk[2 * kc][1], h1, 64);
            const unsigned int e10 = (unsigned int)__shfl((int)pk[2 * kc + 1][0], h0, 64);
            const unsigned int e11 = (unsigned int)__shfl((int)pk[2 * kc + 1][1], h0, 64);
            const unsigned int e12 = (unsigned int)__shfl((int)pk[2 * kc + 1][0], h1, 64);
            const unsigned int e13 = (unsigned int)__shfl((int)pk[2 * kc + 1][1], h1, 64);
            int4 pwv;
            pwv.x = (int)(aSel ? e10 : e00);
            pwv.y = (int)(aSel ? e11 : e01);
            pwv.z = (int)(aSel ? e12 : e02);
            pwv.w = (int)(aSel ? e13 : e03);
            const short8 pf = __builtin_bit_cast(short8, pwv);
            __builtin_amdgcn_s_setprio(1);
            #pragma unroll
            for (int n = 0; n < 8; n++) {
                short8 vf = *reinterpret_cast<const short8*>(
                    Vp + (n * 16 + fr) * 128 + ((kc * 64 + fg * 16) ^ sw));
                oacc[n] = __builtin_amdgcn_mfma_f32_16x16x32_bf16(vf, pf, oacc[n], 0, 0, 0);
            }
            __builtin_amdgcn_s_setprio(0);
        }
        __syncthreads();   // drains this iter's async loads + buffer handoff
    }

    // epilogue: O = O^T / l — lane-local l; packed 8B stores
    const float inv_l = 1.f / l;
    const int orow = qt * 64 + w * 16 + fr;
    #pragma unroll
    for (int n = 0; n < 8; n++) {
        uint2 pko;
        pko.x = (unsigned int)f2bf(oacc[n][0] * inv_l)
              | ((unsigned int)f2bf(oacc[n][1] * inv_l) << 16);
        pko.y = (unsigned int)f2bf(oacc[n][2] * inv_l)
              | ((unsigned int)f2bf(oacc[n][3] * inv_l) << 16);
        *reinterpret_cast<uint2*>(&attno[(size_t)orow * DIM + h * HD + n * 16 + fg * 4]) = pko;
    }
}

// ---------------------------------------------------------------------------
// Output GEMM -> f32 d_out. (unchanged, verified)
// ---------------------------------------------------------------------------
__global__ __launch_bounds__(256) void gemm_out(
    const __hip_bfloat16* __restrict__ A,
    const float* __restrict__ W,
    const float* __restrict__ bias,
    float* __restrict__ outp)
{
    __shared__ __align__(16) short As[128][40];
    __shared__ __align__(16) short Bs[128][40];
    const int bm0 = blockIdx.x * 128;
    const int bn0 = blockIdx.y * 128;
    const int tid = threadIdx.x;
    const int lane = tid & 63;
    const int wid = tid >> 6;
    const int wm = (wid >> 1) * 64;
    const int wn = (wid & 1) * 64;
    const int fr = lane & 15;
    const int fc = (lane >> 4) * 8;
    const int srow = tid >> 3;
    const int scol = (tid & 7) * 4;

    f32x4 acc[4][4] = {};

    for (int kt = 0; kt < DIM; kt += 32) {
        #pragma unroll
        for (int i = 0; i < 2; i++) {
            const int ch = tid + i * 256;
            const int r = ch >> 2, cc = (ch & 3) * 8;
            *reinterpret_cast<int4*>(&As[r][cc]) =
                *reinterpret_cast<const int4*>(&A[(size_t)(bm0 + r) * DIM + kt + cc]);
        }
        #pragma unroll
        for (int p = 0; p < 4; p++) {
            const int r = srow + p * 32;
            float4 vb = *reinterpret_cast<const float4*>(&W[(size_t)(bn0 + r) * DIM + kt + scol]);
            uint2 pb;
            pb.x = (unsigned int)f2bf(vb.x) | ((unsigned int)f2bf(vb.y) << 16);
            pb.y = (unsigned int)f2bf(vb.z) | ((unsigned int)f2bf(vb.w) << 16);
            *reinterpret_cast<uint2*>(&Bs[r][scol]) = pb;
        }
        __syncthreads();
        short8 af[4], bf8[4];
        #pragma unroll
        for (int m = 0; m < 4; m++) af[m]  = *reinterpret_cast<const short8*>(&As[wm + m * 16 + fr][fc]);
        #pragma unroll
        for (int n = 0; n < 4; n++) bf8[n] = *reinterpret_cast<const short8*>(&Bs[wn + n * 16 + fr][fc]);
        #pragma unroll
        for (int m = 0; m < 4; m++)
            #pragma unroll
            for (int n = 0; n < 4; n++)
                acc[m][n] = __builtin_amdgcn_mfma_f32_16x16x32_bf16(af[m], bf8[n], acc[m][n], 0, 0, 0);
        __syncthreads();
    }

    const int crow0 = bm0 + wm + (lane >> 4) * 4;
    const int ccol0 = bn0 + wn + fr;
    #pragma unroll
    for (int n = 0; n < 4; n++) {
        const int col = ccol0 + n * 16;
        const float bb = bias[col];
        #pragma unroll
        for (int m = 0; m < 4; m++)
            #pragma unroll
            for (int r = 0; r < 4; r++)
                outp[(size_t)(crow0 + m * 16 + r) * DIM + col] = acc[m][n][r] + bb;
    }
}

// ---------------------------------------------------------------------------
extern "C" void kernel_launch(void* const* d_in, const int* in_sizes, int n_in,
                              void* d_out, int out_size, void* d_ws, size_t ws_size,
                              hipStream_t stream)
{
    const float* x        = (const float*)d_in[0];
    const int*   seq_lens = (const int*)d_in[1];
    const float* freqs    = (const float*)d_in[3];
    const float* wq = (const float*)d_in[4];
    const float* bq = (const float*)d_in[5];
    const float* wk = (const float*)d_in[6];
    const float* bk = (const float*)d_in[7];
    const float* wv = (const float*)d_in[8];
    const float* bv = (const float*)d_in[9];
    const float* wo = (const float*)d_in[10];
    const float* bo = (const float*)d_in[11];
    const float* gq = (const float*)d_in[12];
    const float* gk = (const float*)d_in[13];
    float* out = (float*)d_out;

    // workspace: 50,331,648 bytes
    //   yq bf16 [0, 12582912) | yk bf16 [12582912, 25165824)
    //   vrow bf16 [25165824, 37748736) (dead after transpose_v; attno aliases)
    //   vT bf16 [37748736, 50331648)
    char* ws = (char*)d_ws;
    __hip_bfloat16* yq    = (__hip_bfloat16*)(ws);
    __hip_bfloat16* yk    = (__hip_bfloat16*)(ws + 12582912);
    __hip_bfloat16* vrow  = (__hip_bfloat16*)(ws + 25165824);
    __hip_bfloat16* vT    = (__hip_bfloat16*)(ws + 37748736);
    __hip_bfloat16* attno = (__hip_bfloat16*)(ws + 25165824);

    dim3 blk(256);
    gemm_qkv    <<<dim3(32, 12, 3), blk, 0, stream>>>(x, wq, bq, wk, bk, wv, bv, yq, yk, vrow);
    rmsnorm_rope<<<dim3(4096, 2),   blk, 0, stream>>>(yq, yk, gq, gk, freqs);
    transpose_v <<<dim3(64, 24),    blk, 0, stream>>>(vrow, vT);
    flash_attn  <<<dim3(64, 12),    blk, 0, stream>>>(yq, yk, vT, seq_lens, attno);
    gemm_out    <<<dim3(32, 12),    blk, 0, stream>>>(attno, wo, bo, out);
}

// Round 14
// 403.491 us; speedup vs baseline: 1.2053x; 1.2053x over previous
//
#include <hip/hip_runtime.h>
#include <hip/hip_bf16.h>

#define DIM   1536
#define HEADS 12
#define HD    128
#define SEQ   4096
#define QSCALE 0.08838834764831845f
#define LOG2E 1.44269504088896f

typedef __attribute__((ext_vector_type(8))) short short8;
typedef __attribute__((ext_vector_type(4))) float f32x4;
typedef __attribute__((ext_vector_type(16))) float f32x16;

__device__ __forceinline__ unsigned short f2bf(float f) {
    __hip_bfloat16 h = __float2bfloat16(f);
    return *reinterpret_cast<unsigned short*>(&h);
}
__device__ __forceinline__ float bf2f(unsigned short u) {
    return __uint_as_float(((unsigned int)u) << 16);
}
__device__ __forceinline__ void async_cp16(void* lds, const void* g) {
    __builtin_amdgcn_global_load_lds(
        (const __attribute__((address_space(1))) unsigned int*)g,
        (__attribute__((address_space(3))) unsigned int*)lds, 16, 0, 0);
}

// ---------------------------------------------------------------------------
// GEMM: y = x @ W^T + b, fused QKV via blockIdx.z. (unchanged, verified)
// ---------------------------------------------------------------------------
__global__ __launch_bounds__(256) void gemm_qkv(
    const float* __restrict__ x,
    const float* __restrict__ wq, const float* __restrict__ bq,
    const float* __restrict__ wk, const float* __restrict__ bk,
    const float* __restrict__ wv, const float* __restrict__ bv,
    __hip_bfloat16* __restrict__ yq, __hip_bfloat16* __restrict__ yk,
    __hip_bfloat16* __restrict__ vrow)
{
    __shared__ __align__(16) short As[128][40];
    __shared__ __align__(16) short Bs[128][40];
    const int z  = blockIdx.z;
    const float* W    = (z == 0) ? wq : (z == 1) ? wk : wv;
    const float* bias = (z == 0) ? bq : (z == 1) ? bk : bv;
    __hip_bfloat16* outp = (z == 0) ? yq : (z == 1) ? yk : vrow;
    const int bm0 = blockIdx.x * 128;
    const int bn0 = blockIdx.y * 128;
    const int tid  = threadIdx.x;
    const int lane = tid & 63;
    const int wid  = tid >> 6;
    const int wm = (wid >> 1) * 64;
    const int wn = (wid & 1)  * 64;
    const int fr = lane & 15;
    const int fc = (lane >> 4) * 8;
    const int srow = tid >> 3;
    const int scol = (tid & 7) * 4;

    f32x4 acc[4][4] = {};

    for (int kt = 0; kt < DIM; kt += 32) {
        #pragma unroll
        for (int p = 0; p < 4; ++p) {
            const int r = srow + p * 32;
            float4 va = *reinterpret_cast<const float4*>(&x[(size_t)(bm0 + r) * DIM + kt + scol]);
            float4 vb = *reinterpret_cast<const float4*>(&W[(size_t)(bn0 + r) * DIM + kt + scol]);
            uint2 pa, pb;
            pa.x = (unsigned int)f2bf(va.x) | ((unsigned int)f2bf(va.y) << 16);
            pa.y = (unsigned int)f2bf(va.z) | ((unsigned int)f2bf(va.w) << 16);
            pb.x = (unsigned int)f2bf(vb.x) | ((unsigned int)f2bf(vb.y) << 16);
            pb.y = (unsigned int)f2bf(vb.z) | ((unsigned int)f2bf(vb.w) << 16);
            *reinterpret_cast<uint2*>(&As[r][scol]) = pa;
            *reinterpret_cast<uint2*>(&Bs[r][scol]) = pb;
        }
        __syncthreads();
        short8 af[4], bf8[4];
        #pragma unroll
        for (int m = 0; m < 4; m++) af[m]  = *reinterpret_cast<const short8*>(&As[wm + m * 16 + fr][fc]);
        #pragma unroll
        for (int n = 0; n < 4; n++) bf8[n] = *reinterpret_cast<const short8*>(&Bs[wn + n * 16 + fr][fc]);
        #pragma unroll
        for (int m = 0; m < 4; m++)
            #pragma unroll
            for (int n = 0; n < 4; n++)
                acc[m][n] = __builtin_amdgcn_mfma_f32_16x16x32_bf16(af[m], bf8[n], acc[m][n], 0, 0, 0);
        __syncthreads();
    }

    const int crow0 = bm0 + wm + (lane >> 4) * 4;
    const int ccol0 = bn0 + wn + fr;
    #pragma unroll
    for (int n = 0; n < 4; n++) {
        const int col = ccol0 + n * 16;
        const float bb = bias[col];
        #pragma unroll
        for (int m = 0; m < 4; m++)
            #pragma unroll
            for (int r = 0; r < 4; r++)
                outp[(size_t)(crow0 + m * 16 + r) * DIM + col] =
                    __float2bfloat16(acc[m][n][r] + bb);
    }
}

// ---------------------------------------------------------------------------
// In-place RMSNorm * g + RoPE. (unchanged, verified)
// ---------------------------------------------------------------------------
__global__ __launch_bounds__(256) void rmsnorm_rope(
    __hip_bfloat16* __restrict__ yq, __hip_bfloat16* __restrict__ yk,
    const float* __restrict__ gq, const float* __restrict__ gk,
    const float* __restrict__ freqs)
{
    const int s = blockIdx.x;
    const int z = blockIdx.y;
    __hip_bfloat16* y = z ? yk : yq;
    const float* g = z ? gk : gq;
    const int t = threadIdx.x;

    float xr[3], xi[3];
    float ss = 0.f;
    #pragma unroll
    for (int i = 0; i < 3; i++) {
        const int p = t + i * 256;
        const unsigned int uu = *reinterpret_cast<const unsigned int*>(&y[(size_t)s * DIM + 2 * p]);
        xr[i] = bf2f((unsigned short)(uu & 0xffffu));
        xi[i] = bf2f((unsigned short)(uu >> 16));
        ss += xr[i] * xr[i] + xi[i] * xi[i];
    }
    #pragma unroll
    for (int m = 1; m < 64; m <<= 1) ss += __shfl_xor(ss, m, 64);
    __shared__ float red[4];
    if ((t & 63) == 0) red[t >> 6] = ss;
    __syncthreads();
    const float sum = red[0] + red[1] + red[2] + red[3];
    const float rs = rsqrtf(sum * (1.0f / DIM) + 1e-6f);
    const int f = s >> 8, hh = (s >> 4) & 15, ww = s & 15;
    const float osc = z ? 1.0f : QSCALE;
    #pragma unroll
    for (int i = 0; i < 3; i++) {
        const int p = t + i * 256;
        const int cc = p & 63;
        const int pos = (cc < 22) ? f : (cc < 43) ? hh : ww;
        const float ang = freqs[pos * 64 + cc];
        float sn, cs;
        sincosf(ang, &sn, &cs);
        const float a = xr[i] * rs * g[2 * p];
        const float b = xi[i] * rs * g[2 * p + 1];
        const unsigned int pk = (unsigned int)f2bf((a * cs - b * sn) * osc)
                              | ((unsigned int)f2bf((a * sn + b * cs) * osc) << 16);
        *reinterpret_cast<unsigned int*>(&y[(size_t)s * DIM + 2 * p]) = pk;
    }
}

// ---------------------------------------------------------------------------
// Transpose V. (unchanged, verified)
// ---------------------------------------------------------------------------
__global__ __launch_bounds__(256) void transpose_v(
    const __hip_bfloat16* __restrict__ vrow,
    __hip_bfloat16* __restrict__ vT)
{
    __shared__ __align__(16) short tile[64][72];
    const int s0 = blockIdx.x * 64;
    const int c0 = blockIdx.y * 64;
    const int t = threadIdx.x;
    #pragma unroll
    for (int i = 0; i < 2; i++) {
        const int ch = t + i * 256;
        const int r = ch >> 3, cc = (ch & 7) * 8;
        *reinterpret_cast<int4*>(&tile[r][cc]) =
            *reinterpret_cast<const int4*>(&vrow[(size_t)(s0 + r) * DIM + c0 + cc]);
    }
    __syncthreads();
    #pragma unroll
    for (int i = 0; i < 2; i++) {
        const int ch = t + i * 256;
        const int c = ch & 63, sc = (ch >> 6) * 8;
        unsigned int w0 = (unsigned short)tile[sc + 0][c] | ((unsigned int)(unsigned short)tile[sc + 1][c] << 16);
        unsigned int w1 = (unsigned short)tile[sc + 2][c] | ((unsigned int)(unsigned short)tile[sc + 3][c] << 16);
        unsigned int w2 = (unsigned short)tile[sc + 4][c] | ((unsigned int)(unsigned short)tile[sc + 5][c] << 16);
        unsigned int w3 = (unsigned short)tile[sc + 6][c] | ((unsigned int)(unsigned short)tile[sc + 7][c] << 16);
        int4 val;
        val.x = (int)w0; val.y = (int)w1; val.z = (int)w2; val.w = (int)w3;
        *reinterpret_cast<int4*>(&vT[(size_t)(c0 + c) * SEQ + s0 + sc]) = val;
    }
}

// ---------------------------------------------------------------------------
// Flash attention v7: 32x32x16 MFMA, QBLK=128 (4 waves x 32 q-rows).
// K/V tiles read once per wave (half the LDS traffic per q of v6).
// Lane pair (l, l+32) shares q-col; P redistribution = 16 shfl_xor(32).
// gload_lds dbuf + swizzle skeleton unchanged (verified v5).
// ---------------------------------------------------------------------------
__global__ __launch_bounds__(256, 2) void flash_attn(
    const __hip_bfloat16* __restrict__ qb,
    const __hip_bfloat16* __restrict__ kb,
    const __hip_bfloat16* __restrict__ vT,
    const int* __restrict__ seq_lens,
    __hip_bfloat16* __restrict__ attno)
{
    __shared__ __align__(16) short Ks[2][64][128];   // 2 x 16 KB, linear
    __shared__ __align__(16) short Vs[2][128][64];   // 2 x 16 KB, linear
    const int qt = blockIdx.x;
    const int h  = blockIdx.y;
    const int tid = threadIdx.x;
    const int lane = tid & 63;
    const int w = tid >> 6;
    const int q5 = lane & 31;
    const int hi = lane >> 5;       // 0/1
    const int seqlen = seq_lens[0];
    const int swz = (lane & 7) << 4;  // read-side XOR (row&7 == lane&7 here)

    // Q fragments (B-operand): col q = q5, k-rows = hi*8+e of d-slice s
    short8 qf[8];
    const int qrow = qt * 128 + w * 32 + q5;
    #pragma unroll
    for (int s = 0; s < 8; s++)
        qf[s] = *reinterpret_cast<const short8*>(&qb[(size_t)qrow * DIM + h * HD + s * 16 + hi * 8]);

    f32x16 oacc[4] = {};         // O^T: oacc[cb][r] = chan cb*32+(r&3)+8*(r>>2)+4*hi, q = q5
    float m = -1e30f, l = 0.f;   // softmax state for q-row (lane-pair shared)

    const int kROW = w * 4 + (lane >> 4);            // + i*16
    const int kCOL = ((lane & 15) ^ (kROW & 7)) * 8; // pre-swizzled source col
    const int vROW = w * 8 + (lane >> 3);            // + i*32
    const int vCOL = (((lane & 7) ^ (vROW & 7))) * 8;

    // prologue: stage tile 0 into buffer 0
    #pragma unroll
    for (int i = 0; i < 4; i++) {
        async_cp16(&Ks[0][i * 16 + w * 4][0],
                   kb + (size_t)(i * 16 + kROW) * DIM + h * HD + kCOL);
        async_cp16(&Vs[0][i * 32 + w * 8][0],
                   vT + ((size_t)h * HD + i * 32 + vROW) * SEQ + vCOL);
    }
    __syncthreads();

    for (int t = 0; t < SEQ / 64; t++) {
        const int cur = t & 1;
        const int kbase = t * 64;
        if (t + 1 < SEQ / 64) {
            const int nb = kbase + 64;
            #pragma unroll
            for (int i = 0; i < 4; i++) {
                async_cp16(&Ks[cur ^ 1][i * 16 + w * 4][0],
                           kb + (size_t)(nb + i * 16 + kROW) * DIM + h * HD + kCOL);
                async_cp16(&Vs[cur ^ 1][i * 32 + w * 8][0],
                           vT + ((size_t)h * HD + i * 32 + vROW) * SEQ + nb + vCOL);
            }
        }
        const char* Kp = (const char*)&Ks[cur][0][0];
        const char* Vp = (const char*)&Vs[cur][0][0];

        // S^T = K Q^T : D[key 32][q 32], 2 key-blocks x 8 d-slices
        f32x16 sacc[2] = {};
        __builtin_amdgcn_s_setprio(1);
        #pragma unroll
        for (int s = 0; s < 8; s++) {
            #pragma unroll
            for (int kbk = 0; kbk < 2; kbk++) {
                short8 kf = *reinterpret_cast<const short8*>(
                    Kp + (kbk * 32 + q5) * 256 + ((s * 32 + hi * 16) ^ swz));
                sacc[kbk] = __builtin_amdgcn_mfma_f32_32x32x16_bf16(kf, qf[s], sacc[kbk], 0, 0, 0);
            }
        }
        __builtin_amdgcn_s_setprio(0);

        // row max over the lane's 32 scores (q = q5; keys split lane-pair)
        float tmax = -1e30f;
        if (kbase + 64 <= seqlen) {
            #pragma unroll
            for (int kbk = 0; kbk < 2; kbk++)
                #pragma unroll
                for (int r = 0; r < 16; r++) tmax = fmaxf(tmax, sacc[kbk][r]);
        } else {
            #pragma unroll
            for (int kbk = 0; kbk < 2; kbk++) {
                #pragma unroll
                for (int r = 0; r < 16; r++) {
                    const int key = kbase + kbk * 32 + (r & 3) + 8 * (r >> 2) + 4 * hi;
                    const float sv = (key < seqlen) ? sacc[kbk][r] : -1e30f;
                    sacc[kbk][r] = sv;
                    tmax = fmaxf(tmax, sv);
                }
            }
        }
        tmax = fmaxf(tmax, __shfl_xor(tmax, 32, 64));

        // defer-max (T13)
        if (!__all(tmax <= m + 8.0f)) {
            const float mn = fmaxf(m, tmax);
            const float alpha = exp2f((m - mn) * LOG2E);
            m = mn;
            l *= alpha;
            #pragma unroll
            for (int cb = 0; cb < 4; cb++)
                #pragma unroll
                for (int r = 0; r < 16; r++) oacc[cb][r] *= alpha;
        }

        // P = exp(S - m); row sum
        float ps = 0.f;
        #pragma unroll
        for (int kbk = 0; kbk < 2; kbk++) {
            #pragma unroll
            for (int r = 0; r < 16; r++) {
                const float p = exp2f((sacc[kbk][r] - m) * LOG2E);
                sacc[kbk][r] = p;
                ps += p;
            }
        }
        ps += __shfl_xor(ps, 32, 64);
        l += ps;

        // pack P: quad (kbk,tq) = keys kbk*32 + 8*tq + 4*hi + {0..3} -> 2 words
        unsigned int W[2][4][2];
        #pragma unroll
        for (int kbk = 0; kbk < 2; kbk++)
            #pragma unroll
            for (int tq = 0; tq < 4; tq++) {
                W[kbk][tq][0] = (unsigned int)f2bf(sacc[kbk][4 * tq + 0])
                              | ((unsigned int)f2bf(sacc[kbk][4 * tq + 1]) << 16);
                W[kbk][tq][1] = (unsigned int)f2bf(sacc[kbk][4 * tq + 2])
                              | ((unsigned int)f2bf(sacc[kbk][4 * tq + 3]) << 16);
            }

        // O^T += V^T P : B-frag(ks) = keys ks*16 + hi*8 + {0..7} for col q5.
        // hi=0: own even-quad + partner even-quad; hi=1: partner odd + own odd.
        #pragma unroll
        for (int ks = 0; ks < 4; ks++) {
            const int kbk = ks >> 1;
            const int te = (ks & 1) * 2, to = te + 1;
            const int a0 = (int)W[kbk][te][0], a1 = (int)W[kbk][te][1];
            const int b0 = (int)W[kbk][to][0], b1 = (int)W[kbk][to][1];
            const int xa0 = __shfl_xor(a0, 32, 64);
            const int xa1 = __shfl_xor(a1, 32, 64);
            const int xb0 = __shfl_xor(b0, 32, 64);
            const int xb1 = __shfl_xor(b1, 32, 64);
            int4 pwv;
            pwv.x = hi ? xb0 : a0;
            pwv.y = hi ? xb1 : a1;
            pwv.z = hi ? b0  : xa0;
            pwv.w = hi ? b1  : xa1;
            const short8 pf = __builtin_bit_cast(short8, pwv);
            __builtin_amdgcn_s_setprio(1);
            #pragma unroll
            for (int cb = 0; cb < 4; cb++) {
                short8 vf = *reinterpret_cast<const short8*>(
                    Vp + (cb * 32 + q5) * 128 + ((ks * 32 + hi * 16) ^ swz));
                oacc[cb] = __builtin_amdgcn_mfma_f32_32x32x16_bf16(vf, pf, oacc[cb], 0, 0, 0);
            }
            __builtin_amdgcn_s_setprio(0);
        }
        __syncthreads();   // drains this iter's async loads + buffer handoff
    }

    // epilogue: O = O^T / l, packed 8B stores (chans cb*32 + 8t + 4hi + 0..3)
    const float inv_l = 1.f / l;
    const size_t obase = (size_t)qrow * DIM + h * HD;
    #pragma unroll
    for (int cb = 0; cb < 4; cb++) {
        #pragma unroll
        for (int tq = 0; tq < 4; tq++) {
            uint2 pko;
            pko.x = (unsigned int)f2bf(oacc[cb][4 * tq + 0] * inv_l)
                  | ((unsigned int)f2bf(oacc[cb][4 * tq + 1] * inv_l) << 16);
            pko.y = (unsigned int)f2bf(oacc[cb][4 * tq + 2] * inv_l)
                  | ((unsigned int)f2bf(oacc[cb][4 * tq + 3] * inv_l) << 16);
            *reinterpret_cast<uint2*>(&attno[obase + cb * 32 + 8 * tq + 4 * hi]) = pko;
        }
    }
}

// ---------------------------------------------------------------------------
// Output GEMM -> f32 d_out. (unchanged, verified)
// ---------------------------------------------------------------------------
__global__ __launch_bounds__(256) void gemm_out(
    const __hip_bfloat16* __restrict__ A,
    const float* __restrict__ W,
    const float* __restrict__ bias,
    float* __restrict__ outp)
{
    __shared__ __align__(16) short As[128][40];
    __shared__ __align__(16) short Bs[128][40];
    const int bm0 = blockIdx.x * 128;
    const int bn0 = blockIdx.y * 128;
    const int tid = threadIdx.x;
    const int lane = tid & 63;
    const int wid = tid >> 6;
    const int wm = (wid >> 1) * 64;
    const int wn = (wid & 1) * 64;
    const int fr = lane & 15;
    const int fc = (lane >> 4) * 8;
    const int srow = tid >> 3;
    const int scol = (tid & 7) * 4;

    f32x4 acc[4][4] = {};

    for (int kt = 0; kt < DIM; kt += 32) {
        #pragma unroll
        for (int i = 0; i < 2; i++) {
            const int ch = tid + i * 256;
            const int r = ch >> 2, cc = (ch & 3) * 8;
            *reinterpret_cast<int4*>(&As[r][cc]) =
                *reinterpret_cast<const int4*>(&A[(size_t)(bm0 + r) * DIM + kt + cc]);
        }
        #pragma unroll
        for (int p = 0; p < 4; p++) {
            const int r = srow + p * 32;
            float4 vb = *reinterpret_cast<const float4*>(&W[(size_t)(bn0 + r) * DIM + kt + scol]);
            uint2 pb;
            pb.x = (unsigned int)f2bf(vb.x) | ((unsigned int)f2bf(vb.y) << 16);
            pb.y = (unsigned int)f2bf(vb.z) | ((unsigned int)f2bf(vb.w) << 16);
            *reinterpret_cast<uint2*>(&Bs[r][scol]) = pb;
        }
        __syncthreads();
        short8 af[4], bf8[4];
        #pragma unroll
        for (int m = 0; m < 4; m++) af[m]  = *reinterpret_cast<const short8*>(&As[wm + m * 16 + fr][fc]);
        #pragma unroll
        for (int n = 0; n < 4; n++) bf8[n] = *reinterpret_cast<const short8*>(&Bs[wn + n * 16 + fr][fc]);
        #pragma unroll
        for (int m = 0; m < 4; m++)
            #pragma unroll
            for (int n = 0; n < 4; n++)
                acc[m][n] = __builtin_amdgcn_mfma_f32_16x16x32_bf16(af[m], bf8[n], acc[m][n], 0, 0, 0);
        __syncthreads();
    }

    const int crow0 = bm0 + wm + (lane >> 4) * 4;
    const int ccol0 = bn0 + wn + fr;
    #pragma unroll
    for (int n = 0; n < 4; n++) {
        const int col = ccol0 + n * 16;
        const float bb = bias[col];
        #pragma unroll
        for (int m = 0; m < 4; m++)
            #pragma unroll
            for (int r = 0; r < 4; r++)
                outp[(size_t)(crow0 + m * 16 + r) * DIM + col] = acc[m][n][r] + bb;
    }
}

// ---------------------------------------------------------------------------
extern "C" void kernel_launch(void* const* d_in, const int* in_sizes, int n_in,
                              void* d_out, int out_size, void* d_ws, size_t ws_size,
                              hipStream_t stream)
{
    const float* x        = (const float*)d_in[0];
    const int*   seq_lens = (const int*)d_in[1];
    const float* freqs    = (const float*)d_in[3];
    const float* wq = (const float*)d_in[4];
    const float* bq = (const float*)d_in[5];
    const float* wk = (const float*)d_in[6];
    const float* bk = (const float*)d_in[7];
    const float* wv = (const float*)d_in[8];
    const float* bv = (const float*)d_in[9];
    const float* wo = (const float*)d_in[10];
    const float* bo = (const float*)d_in[11];
    const float* gq = (const float*)d_in[12];
    const float* gk = (const float*)d_in[13];
    float* out = (float*)d_out;

    // workspace: 50,331,648 bytes
    //   yq bf16 [0, 12582912) | yk bf16 [12582912, 25165824)
    //   vrow bf16 [25165824, 37748736) (dead after transpose_v; attno aliases)
    //   vT bf16 [37748736, 50331648)
    char* ws = (char*)d_ws;
    __hip_bfloat16* yq    = (__hip_bfloat16*)(ws);
    __hip_bfloat16* yk    = (__hip_bfloat16*)(ws + 12582912);
    __hip_bfloat16* vrow  = (__hip_bfloat16*)(ws + 25165824);
    __hip_bfloat16* vT    = (__hip_bfloat16*)(ws + 37748736);
    __hip_bfloat16* attno = (__hip_bfloat16*)(ws + 25165824);

    dim3 blk(256);
    gemm_qkv    <<<dim3(32, 12, 3), blk, 0, stream>>>(x, wq, bq, wk, bk, wv, bv, yq, yk, vrow);
    rmsnorm_rope<<<dim3(4096, 2),   blk, 0, stream>>>(yq, yk, gq, gk, freqs);
    transpose_v <<<dim3(64, 24),    blk, 0, stream>>>(vrow, vT);
    flash_attn  <<<dim3(32, 12),    blk, 0, stream>>>(yq, yk, vT, seq_lens, attno);
    gemm_out    <<<dim3(32, 12),    blk, 0, stream>>>(attno, wo, bo, out);
}

// Round 15
// 358.675 us; speedup vs baseline: 1.3559x; 1.1250x over previous
//
#include <hip/hip_runtime.h>
#include <hip/hip_bf16.h>

#define DIM   1536
#define HEADS 12
#define HD    128
#define SEQ   4096
#define QSCALE 0.08838834764831845f
#define LOG2E 1.44269504088896f

typedef __attribute__((ext_vector_type(8))) short short8;
typedef __attribute__((ext_vector_type(4))) float f32x4;
typedef __attribute__((ext_vector_type(16))) float f32x16;

__device__ __forceinline__ unsigned short f2bf(float f) {
    __hip_bfloat16 h = __float2bfloat16(f);
    return *reinterpret_cast<unsigned short*>(&h);
}
__device__ __forceinline__ float bf2f(unsigned short u) {
    return __uint_as_float(((unsigned int)u) << 16);
}
__device__ __forceinline__ void async_cp16(void* lds, const void* g) {
    __builtin_amdgcn_global_load_lds(
        (const __attribute__((address_space(1))) unsigned int*)g,
        (__attribute__((address_space(3))) unsigned int*)lds, 16, 0, 0);
}

// ---------------------------------------------------------------------------
// f32 -> bf16 convert, 8 elements/thread.
// ---------------------------------------------------------------------------
__global__ __launch_bounds__(256) void convert_bf16(
    const float* __restrict__ src, __hip_bfloat16* __restrict__ dst, int n8)
{
    const int i = blockIdx.x * 256 + threadIdx.x;
    if (i >= n8) return;
    const float4 a = *reinterpret_cast<const float4*>(src + (size_t)i * 8);
    const float4 b = *reinterpret_cast<const float4*>(src + (size_t)i * 8 + 4);
    uint4 o;
    o.x = (unsigned int)f2bf(a.x) | ((unsigned int)f2bf(a.y) << 16);
    o.y = (unsigned int)f2bf(a.z) | ((unsigned int)f2bf(a.w) << 16);
    o.z = (unsigned int)f2bf(b.x) | ((unsigned int)f2bf(b.y) << 16);
    o.w = (unsigned int)f2bf(b.z) | ((unsigned int)f2bf(b.w) << 16);
    *reinterpret_cast<uint4*>(dst + (size_t)i * 8) = o;
}

// ---------------------------------------------------------------------------
// GEMM (m97-style): y = A(bf16) @ W(bf16)^T + b -> bf16.
// 128x128 tile, BK=32, global_load_lds(16B) staging, linear LDS.
// Fused QKV via blockIdx.z.
// ---------------------------------------------------------------------------
__global__ __launch_bounds__(256) void gemm_qkv(
    const __hip_bfloat16* __restrict__ xb,
    const __hip_bfloat16* __restrict__ wqb, const float* __restrict__ bq,
    const __hip_bfloat16* __restrict__ wkb, const float* __restrict__ bk,
    const __hip_bfloat16* __restrict__ wvb, const float* __restrict__ bv,
    __hip_bfloat16* __restrict__ yq, __hip_bfloat16* __restrict__ yk,
    __hip_bfloat16* __restrict__ vrow)
{
    __shared__ __align__(16) short As[128][32];
    __shared__ __align__(16) short Bs[128][32];
    const int z  = blockIdx.z;
    const __hip_bfloat16* W = (z == 0) ? wqb : (z == 1) ? wkb : wvb;
    const float* bias = (z == 0) ? bq : (z == 1) ? bk : bv;
    __hip_bfloat16* outp = (z == 0) ? yq : (z == 1) ? yk : vrow;
    const int bm0 = blockIdx.x * 128;
    const int bn0 = blockIdx.y * 128;
    const int tid  = threadIdx.x;
    const int lane = tid & 63;
    const int wid  = tid >> 6;
    const int wm = (wid >> 1) * 64;
    const int wn = (wid & 1)  * 64;
    const int fr = lane & 15;
    const int fc = (lane >> 4) * 8;
    const int srow = tid >> 2;          // 0..63 (row within 64-row half)
    const int scol = (tid & 3) * 8;     // element col

    f32x4 acc[4][4] = {};

    for (int kt = 0; kt < DIM; kt += 32) {
        #pragma unroll
        for (int i = 0; i < 2; i++) {
            async_cp16(&As[i * 64 + ((tid >> 6) << 4)][0],
                       xb + (size_t)(bm0 + i * 64 + srow) * DIM + kt + scol);
            async_cp16(&Bs[i * 64 + ((tid >> 6) << 4)][0],
                       W + (size_t)(bn0 + i * 64 + srow) * DIM + kt + scol);
        }
        __syncthreads();
        short8 af[4], bf8[4];
        #pragma unroll
        for (int m = 0; m < 4; m++) af[m]  = *reinterpret_cast<const short8*>(&As[wm + m * 16 + fr][fc]);
        #pragma unroll
        for (int n = 0; n < 4; n++) bf8[n] = *reinterpret_cast<const short8*>(&Bs[wn + n * 16 + fr][fc]);
        #pragma unroll
        for (int m = 0; m < 4; m++)
            #pragma unroll
            for (int n = 0; n < 4; n++)
                acc[m][n] = __builtin_amdgcn_mfma_f32_16x16x32_bf16(af[m], bf8[n], acc[m][n], 0, 0, 0);
        __syncthreads();
    }

    const int crow0 = bm0 + wm + (lane >> 4) * 4;
    const int ccol0 = bn0 + wn + fr;
    #pragma unroll
    for (int n = 0; n < 4; n++) {
        const int col = ccol0 + n * 16;
        const float bb = bias[col];
        #pragma unroll
        for (int m = 0; m < 4; m++)
            #pragma unroll
            for (int r = 0; r < 4; r++)
                outp[(size_t)(crow0 + m * 16 + r) * DIM + col] =
                    __float2bfloat16(acc[m][n][r] + bb);
    }
}

// ---------------------------------------------------------------------------
// In-place RMSNorm * g + RoPE. (unchanged, verified)
// ---------------------------------------------------------------------------
__global__ __launch_bounds__(256) void rmsnorm_rope(
    __hip_bfloat16* __restrict__ yq, __hip_bfloat16* __restrict__ yk,
    const float* __restrict__ gq, const float* __restrict__ gk,
    const float* __restrict__ freqs)
{
    const int s = blockIdx.x;
    const int z = blockIdx.y;
    __hip_bfloat16* y = z ? yk : yq;
    const float* g = z ? gk : gq;
    const int t = threadIdx.x;

    float xr[3], xi[3];
    float ss = 0.f;
    #pragma unroll
    for (int i = 0; i < 3; i++) {
        const int p = t + i * 256;
        const unsigned int uu = *reinterpret_cast<const unsigned int*>(&y[(size_t)s * DIM + 2 * p]);
        xr[i] = bf2f((unsigned short)(uu & 0xffffu));
        xi[i] = bf2f((unsigned short)(uu >> 16));
        ss += xr[i] * xr[i] + xi[i] * xi[i];
    }
    #pragma unroll
    for (int m = 1; m < 64; m <<= 1) ss += __shfl_xor(ss, m, 64);
    __shared__ float red[4];
    if ((t & 63) == 0) red[t >> 6] = ss;
    __syncthreads();
    const float sum = red[0] + red[1] + red[2] + red[3];
    const float rs = rsqrtf(sum * (1.0f / DIM) + 1e-6f);
    const int f = s >> 8, hh = (s >> 4) & 15, ww = s & 15;
    const float osc = z ? 1.0f : QSCALE;
    #pragma unroll
    for (int i = 0; i < 3; i++) {
        const int p = t + i * 256;
        const int cc = p & 63;
        const int pos = (cc < 22) ? f : (cc < 43) ? hh : ww;
        const float ang = freqs[pos * 64 + cc];
        float sn, cs;
        sincosf(ang, &sn, &cs);
        const float a = xr[i] * rs * g[2 * p];
        const float b = xi[i] * rs * g[2 * p + 1];
        const unsigned int pk = (unsigned int)f2bf((a * cs - b * sn) * osc)
                              | ((unsigned int)f2bf((a * sn + b * cs) * osc) << 16);
        *reinterpret_cast<unsigned int*>(&y[(size_t)s * DIM + 2 * p]) = pk;
    }
}

// ---------------------------------------------------------------------------
// Transpose V. (unchanged, verified)
// ---------------------------------------------------------------------------
__global__ __launch_bounds__(256) void transpose_v(
    const __hip_bfloat16* __restrict__ vrow,
    __hip_bfloat16* __restrict__ vT)
{
    __shared__ __align__(16) short tile[64][72];
    const int s0 = blockIdx.x * 64;
    const int c0 = blockIdx.y * 64;
    const int t = threadIdx.x;
    #pragma unroll
    for (int i = 0; i < 2; i++) {
        const int ch = t + i * 256;
        const int r = ch >> 3, cc = (ch & 7) * 8;
        *reinterpret_cast<int4*>(&tile[r][cc]) =
            *reinterpret_cast<const int4*>(&vrow[(size_t)(s0 + r) * DIM + c0 + cc]);
    }
    __syncthreads();
    #pragma unroll
    for (int i = 0; i < 2; i++) {
        const int ch = t + i * 256;
        const int c = ch & 63, sc = (ch >> 6) * 8;
        unsigned int w0 = (unsigned short)tile[sc + 0][c] | ((unsigned int)(unsigned short)tile[sc + 1][c] << 16);
        unsigned int w1 = (unsigned short)tile[sc + 2][c] | ((unsigned int)(unsigned short)tile[sc + 3][c] << 16);
        unsigned int w2 = (unsigned short)tile[sc + 4][c] | ((unsigned int)(unsigned short)tile[sc + 5][c] << 16);
        unsigned int w3 = (unsigned short)tile[sc + 6][c] | ((unsigned int)(unsigned short)tile[sc + 7][c] << 16);
        int4 val;
        val.x = (int)w0; val.y = (int)w1; val.z = (int)w2; val.w = (int)w3;
        *reinterpret_cast<int4*>(&vT[(size_t)(c0 + c) * SEQ + s0 + sc]) = val;
    }
}

// ---------------------------------------------------------------------------
// Flash attention v7 (unchanged, verified round 14): 32x32x16, QBLK=128.
// ---------------------------------------------------------------------------
__global__ __launch_bounds__(256, 2) void flash_attn(
    const __hip_bfloat16* __restrict__ qb,
    const __hip_bfloat16* __restrict__ kb,
    const __hip_bfloat16* __restrict__ vT,
    const int* __restrict__ seq_lens,
    __hip_bfloat16* __restrict__ attno)
{
    __shared__ __align__(16) short Ks[2][64][128];
    __shared__ __align__(16) short Vs[2][128][64];
    const int qt = blockIdx.x;
    const int h  = blockIdx.y;
    const int tid = threadIdx.x;
    const int lane = tid & 63;
    const int w = tid >> 6;
    const int q5 = lane & 31;
    const int hi = lane >> 5;
    const int seqlen = seq_lens[0];
    const int swz = (lane & 7) << 4;

    short8 qf[8];
    const int qrow = qt * 128 + w * 32 + q5;
    #pragma unroll
    for (int s = 0; s < 8; s++)
        qf[s] = *reinterpret_cast<const short8*>(&qb[(size_t)qrow * DIM + h * HD + s * 16 + hi * 8]);

    f32x16 oacc[4] = {};
    float m = -1e30f, l = 0.f;

    const int kROW = w * 4 + (lane >> 4);
    const int kCOL = ((lane & 15) ^ (kROW & 7)) * 8;
    const int vROW = w * 8 + (lane >> 3);
    const int vCOL = (((lane & 7) ^ (vROW & 7))) * 8;

    #pragma unroll
    for (int i = 0; i < 4; i++) {
        async_cp16(&Ks[0][i * 16 + w * 4][0],
                   kb + (size_t)(i * 16 + kROW) * DIM + h * HD + kCOL);
        async_cp16(&Vs[0][i * 32 + w * 8][0],
                   vT + ((size_t)h * HD + i * 32 + vROW) * SEQ + vCOL);
    }
    __syncthreads();

    for (int t = 0; t < SEQ / 64; t++) {
        const int cur = t & 1;
        const int kbase = t * 64;
        if (t + 1 < SEQ / 64) {
            const int nb = kbase + 64;
            #pragma unroll
            for (int i = 0; i < 4; i++) {
                async_cp16(&Ks[cur ^ 1][i * 16 + w * 4][0],
                           kb + (size_t)(nb + i * 16 + kROW) * DIM + h * HD + kCOL);
                async_cp16(&Vs[cur ^ 1][i * 32 + w * 8][0],
                           vT + ((size_t)h * HD + i * 32 + vROW) * SEQ + nb + vCOL);
            }
        }
        const char* Kp = (const char*)&Ks[cur][0][0];
        const char* Vp = (const char*)&Vs[cur][0][0];

        f32x16 sacc[2] = {};
        __builtin_amdgcn_s_setprio(1);
        #pragma unroll
        for (int s = 0; s < 8; s++) {
            #pragma unroll
            for (int kbk = 0; kbk < 2; kbk++) {
                short8 kf = *reinterpret_cast<const short8*>(
                    Kp + (kbk * 32 + q5) * 256 + ((s * 32 + hi * 16) ^ swz));
                sacc[kbk] = __builtin_amdgcn_mfma_f32_32x32x16_bf16(kf, qf[s], sacc[kbk], 0, 0, 0);
            }
        }
        __builtin_amdgcn_s_setprio(0);

        float tmax = -1e30f;
        if (kbase + 64 <= seqlen) {
            #pragma unroll
            for (int kbk = 0; kbk < 2; kbk++)
                #pragma unroll
                for (int r = 0; r < 16; r++) tmax = fmaxf(tmax, sacc[kbk][r]);
        } else {
            #pragma unroll
            for (int kbk = 0; kbk < 2; kbk++) {
                #pragma unroll
                for (int r = 0; r < 16; r++) {
                    const int key = kbase + kbk * 32 + (r & 3) + 8 * (r >> 2) + 4 * hi;
                    const float sv = (key < seqlen) ? sacc[kbk][r] : -1e30f;
                    sacc[kbk][r] = sv;
                    tmax = fmaxf(tmax, sv);
                }
            }
        }
        tmax = fmaxf(tmax, __shfl_xor(tmax, 32, 64));

        if (!__all(tmax <= m + 8.0f)) {
            const float mn = fmaxf(m, tmax);
            const float alpha = exp2f((m - mn) * LOG2E);
            m = mn;
            l *= alpha;
            #pragma unroll
            for (int cb = 0; cb < 4; cb++)
                #pragma unroll
                for (int r = 0; r < 16; r++) oacc[cb][r] *= alpha;
        }

        float ps = 0.f;
        #pragma unroll
        for (int kbk = 0; kbk < 2; kbk++) {
            #pragma unroll
            for (int r = 0; r < 16; r++) {
                const float p = exp2f((sacc[kbk][r] - m) * LOG2E);
                sacc[kbk][r] = p;
                ps += p;
            }
        }
        ps += __shfl_xor(ps, 32, 64);
        l += ps;

        unsigned int W[2][4][2];
        #pragma unroll
        for (int kbk = 0; kbk < 2; kbk++)
            #pragma unroll
            for (int tq = 0; tq < 4; tq++) {
                W[kbk][tq][0] = (unsigned int)f2bf(sacc[kbk][4 * tq + 0])
                              | ((unsigned int)f2bf(sacc[kbk][4 * tq + 1]) << 16);
                W[kbk][tq][1] = (unsigned int)f2bf(sacc[kbk][4 * tq + 2])
                              | ((unsigned int)f2bf(sacc[kbk][4 * tq + 3]) << 16);
            }

        #pragma unroll
        for (int ks = 0; ks < 4; ks++) {
            const int kbk = ks >> 1;
            const int te = (ks & 1) * 2, to = te + 1;
            const int a0 = (int)W[kbk][te][0], a1 = (int)W[kbk][te][1];
            const int b0 = (int)W[kbk][to][0], b1 = (int)W[kbk][to][1];
            const int xa0 = __shfl_xor(a0, 32, 64);
            const int xa1 = __shfl_xor(a1, 32, 64);
            const int xb0 = __shfl_xor(b0, 32, 64);
            const int xb1 = __shfl_xor(b1, 32, 64);
            int4 pwv;
            pwv.x = hi ? xb0 : a0;
            pwv.y = hi ? xb1 : a1;
            pwv.z = hi ? b0  : xa0;
            pwv.w = hi ? b1  : xa1;
            const short8 pf = __builtin_bit_cast(short8, pwv);
            __builtin_amdgcn_s_setprio(1);
            #pragma unroll
            for (int cb = 0; cb < 4; cb++) {
                short8 vf = *reinterpret_cast<const short8*>(
                    Vp + (cb * 32 + q5) * 128 + ((ks * 32 + hi * 16) ^ swz));
                oacc[cb] = __builtin_amdgcn_mfma_f32_32x32x16_bf16(vf, pf, oacc[cb], 0, 0, 0);
            }
            __builtin_amdgcn_s_setprio(0);
        }
        __syncthreads();
    }

    const float inv_l = 1.f / l;
    const size_t obase = (size_t)qrow * DIM + h * HD;
    #pragma unroll
    for (int cb = 0; cb < 4; cb++) {
        #pragma unroll
        for (int tq = 0; tq < 4; tq++) {
            uint2 pko;
            pko.x = (unsigned int)f2bf(oacc[cb][4 * tq + 0] * inv_l)
                  | ((unsigned int)f2bf(oacc[cb][4 * tq + 1] * inv_l) << 16);
            pko.y = (unsigned int)f2bf(oacc[cb][4 * tq + 2] * inv_l)
                  | ((unsigned int)f2bf(oacc[cb][4 * tq + 3] * inv_l) << 16);
            *reinterpret_cast<uint2*>(&attno[obase + cb * 32 + 8 * tq + 4 * hi]) = pko;
        }
    }
}

// ---------------------------------------------------------------------------
// Output GEMM (m97-style staging): out = attno(bf16) @ wob(bf16)^T + bo -> f32.
// ---------------------------------------------------------------------------
__global__ __launch_bounds__(256) void gemm_out(
    const __hip_bfloat16* __restrict__ A,
    const __hip_bfloat16* __restrict__ W,
    const float* __restrict__ bias,
    float* __restrict__ outp)
{
    __shared__ __align__(16) short As[128][32];
    __shared__ __align__(16) short Bs[128][32];
    const int bm0 = blockIdx.x * 128;
    const int bn0 = blockIdx.y * 128;
    const int tid = threadIdx.x;
    const int lane = tid & 63;
    const int wid = tid >> 6;
    const int wm = (wid >> 1) * 64;
    const int wn = (wid & 1) * 64;
    const int fr = lane & 15;
    const int fc = (lane >> 4) * 8;
    const int srow = tid >> 2;
    const int scol = (tid & 3) * 8;

    f32x4 acc[4][4] = {};

    for (int kt = 0; kt < DIM; kt += 32) {
        #pragma unroll
        for (int i = 0; i < 2; i++) {
            async_cp16(&As[i * 64 + ((tid >> 6) << 4)][0],
                       A + (size_t)(bm0 + i * 64 + srow) * DIM + kt + scol);
            async_cp16(&Bs[i * 64 + ((tid >> 6) << 4)][0],
                       W + (size_t)(bn0 + i * 64 + srow) * DIM + kt + scol);
        }
        __syncthreads();
        short8 af[4], bf8[4];
        #pragma unroll
        for (int m = 0; m < 4; m++) af[m]  = *reinterpret_cast<const short8*>(&As[wm + m * 16 + fr][fc]);
        #pragma unroll
        for (int n = 0; n < 4; n++) bf8[n] = *reinterpret_cast<const short8*>(&Bs[wn + n * 16 + fr][fc]);
        #pragma unroll
        for (int m = 0; m < 4; m++)
            #pragma unroll
            for (int n = 0; n < 4; n++)
                acc[m][n] = __builtin_amdgcn_mfma_f32_16x16x32_bf16(af[m], bf8[n], acc[m][n], 0, 0, 0);
        __syncthreads();
    }

    const int crow0 = bm0 + wm + (lane >> 4) * 4;
    const int ccol0 = bn0 + wn + fr;
    #pragma unroll
    for (int n = 0; n < 4; n++) {
        const int col = ccol0 + n * 16;
        const float bb = bias[col];
        #pragma unroll
        for (int m = 0; m < 4; m++)
            #pragma unroll
            for (int r = 0; r < 4; r++)
                outp[(size_t)(crow0 + m * 16 + r) * DIM + col] = acc[m][n][r] + bb;
    }
}

// ---------------------------------------------------------------------------
extern "C" void kernel_launch(void* const* d_in, const int* in_sizes, int n_in,
                              void* d_out, int out_size, void* d_ws, size_t ws_size,
                              hipStream_t stream)
{
    const float* x        = (const float*)d_in[0];
    const int*   seq_lens = (const int*)d_in[1];
    const float* freqs    = (const float*)d_in[3];
    const float* wq = (const float*)d_in[4];
    const float* bq = (const float*)d_in[5];
    const float* wk = (const float*)d_in[6];
    const float* bk = (const float*)d_in[7];
    const float* wv = (const float*)d_in[8];
    const float* bv = (const float*)d_in[9];
    const float* wo = (const float*)d_in[10];
    const float* bo = (const float*)d_in[11];
    const float* gq = (const float*)d_in[12];
    const float* gk = (const float*)d_in[13];
    float* out = (float*)d_out;

    // workspace (50,331,648 bytes, unchanged) + d_out used as early scratch:
    //   yq bf16 [0, 12582912)          (q; dead after flash -> wob aliases)
    //   yk bf16 [12582912, 25165824)
    //   vrow bf16 [25165824, 37748736) (dead after transpose_v; attno aliases)
    //   vT bf16 [37748736, 50331648)   (xb lives here until transpose_v)
    //   wq/wk/wv bf16 -> d_out[0..14155776) (scratch until gemm_out writes)
    char* ws = (char*)d_ws;
    __hip_bfloat16* yq    = (__hip_bfloat16*)(ws);
    __hip_bfloat16* yk    = (__hip_bfloat16*)(ws + 12582912);
    __hip_bfloat16* vrow  = (__hip_bfloat16*)(ws + 25165824);
    __hip_bfloat16* vT    = (__hip_bfloat16*)(ws + 37748736);
    __hip_bfloat16* attno = (__hip_bfloat16*)(ws + 25165824);
    __hip_bfloat16* xb    = (__hip_bfloat16*)(ws + 37748736);   // aliases vT (dead until transpose)
    __hip_bfloat16* wob   = (__hip_bfloat16*)(ws);              // aliases yq (dead after flash)
    __hip_bfloat16* wqb   = (__hip_bfloat16*)d_out;
    __hip_bfloat16* wkb   = wqb + 2359296;
    __hip_bfloat16* wvb   = wkb + 2359296;

    dim3 blk(256);
    convert_bf16<<<dim3(3072), blk, 0, stream>>>(x,  xb,  786432);
    convert_bf16<<<dim3(1152), blk, 0, stream>>>(wq, wqb, 294912);
    convert_bf16<<<dim3(1152), blk, 0, stream>>>(wk, wkb, 294912);
    convert_bf16<<<dim3(1152), blk, 0, stream>>>(wv, wvb, 294912);
    gemm_qkv    <<<dim3(32, 12, 3), blk, 0, stream>>>(xb, wqb, bq, wkb, bk, wvb, bv, yq, yk, vrow);
    rmsnorm_rope<<<dim3(4096, 2),   blk, 0, stream>>>(yq, yk, gq, gk, freqs);
    transpose_v <<<dim3(64, 24),    blk, 0, stream>>>(vrow, vT);
    flash_attn  <<<dim3(32, 12),    blk, 0, stream>>>(yq, yk, vT, seq_lens, attno);
    convert_bf16<<<dim3(1152), blk, 0, stream>>>(wo, wob, 294912);
    gemm_out    <<<dim3(32, 12),    blk, 0, stream>>>(attno, wob, bo, out);
}

// Round 16
// 356.895 us; speedup vs baseline: 1.3627x; 1.0050x over previous
//
#include <hip/hip_runtime.h>
#include <hip/hip_bf16.h>

#define DIM   1536
#define HEADS 12
#define HD    128
#define SEQ   4096
#define QSCALE 0.08838834764831845f
#define LOG2E 1.44269504088896f

typedef __attribute__((ext_vector_type(8))) short short8;
typedef __attribute__((ext_vector_type(4))) float f32x4;
typedef __attribute__((ext_vector_type(16))) float f32x16;

__device__ __forceinline__ unsigned short f2bf(float f) {
    __hip_bfloat16 h = __float2bfloat16(f);
    return *reinterpret_cast<unsigned short*>(&h);
}
__device__ __forceinline__ float bf2f(unsigned short u) {
    return __uint_as_float(((unsigned int)u) << 16);
}
__device__ __forceinline__ void async_cp16(void* lds, const void* g) {
    __builtin_amdgcn_global_load_lds(
        (const __attribute__((address_space(1))) unsigned int*)g,
        (__attribute__((address_space(3))) unsigned int*)lds, 16, 0, 0);
}

// ---------------------------------------------------------------------------
// f32 -> bf16 convert, 8 elements/thread. (unchanged, verified)
// ---------------------------------------------------------------------------
__global__ __launch_bounds__(256) void convert_bf16(
    const float* __restrict__ src, __hip_bfloat16* __restrict__ dst, int n8)
{
    const int i = blockIdx.x * 256 + threadIdx.x;
    if (i >= n8) return;
    const float4 a = *reinterpret_cast<const float4*>(src + (size_t)i * 8);
    const float4 b = *reinterpret_cast<const float4*>(src + (size_t)i * 8 + 4);
    uint4 o;
    o.x = (unsigned int)f2bf(a.x) | ((unsigned int)f2bf(a.y) << 16);
    o.y = (unsigned int)f2bf(a.z) | ((unsigned int)f2bf(a.w) << 16);
    o.z = (unsigned int)f2bf(b.x) | ((unsigned int)f2bf(b.y) << 16);
    o.w = (unsigned int)f2bf(b.z) | ((unsigned int)f2bf(b.w) << 16);
    *reinterpret_cast<uint4*>(dst + (size_t)i * 8) = o;
}

// ---------------------------------------------------------------------------
// GEMM (m97-style): y = A(bf16) @ W(bf16)^T + b -> bf16. (unchanged, verified)
// ---------------------------------------------------------------------------
__global__ __launch_bounds__(256) void gemm_qkv(
    const __hip_bfloat16* __restrict__ xb,
    const __hip_bfloat16* __restrict__ wqb, const float* __restrict__ bq,
    const __hip_bfloat16* __restrict__ wkb, const float* __restrict__ bk,
    const __hip_bfloat16* __restrict__ wvb, const float* __restrict__ bv,
    __hip_bfloat16* __restrict__ yq, __hip_bfloat16* __restrict__ yk,
    __hip_bfloat16* __restrict__ vrow)
{
    __shared__ __align__(16) short As[128][32];
    __shared__ __align__(16) short Bs[128][32];
    const int z  = blockIdx.z;
    const __hip_bfloat16* W = (z == 0) ? wqb : (z == 1) ? wkb : wvb;
    const float* bias = (z == 0) ? bq : (z == 1) ? bk : bv;
    __hip_bfloat16* outp = (z == 0) ? yq : (z == 1) ? yk : vrow;
    const int bm0 = blockIdx.x * 128;
    const int bn0 = blockIdx.y * 128;
    const int tid  = threadIdx.x;
    const int lane = tid & 63;
    const int wid  = tid >> 6;
    const int wm = (wid >> 1) * 64;
    const int wn = (wid & 1)  * 64;
    const int fr = lane & 15;
    const int fc = (lane >> 4) * 8;
    const int srow = tid >> 2;
    const int scol = (tid & 3) * 8;

    f32x4 acc[4][4] = {};

    for (int kt = 0; kt < DIM; kt += 32) {
        #pragma unroll
        for (int i = 0; i < 2; i++) {
            async_cp16(&As[i * 64 + ((tid >> 6) << 4)][0],
                       xb + (size_t)(bm0 + i * 64 + srow) * DIM + kt + scol);
            async_cp16(&Bs[i * 64 + ((tid >> 6) << 4)][0],
                       W + (size_t)(bn0 + i * 64 + srow) * DIM + kt + scol);
        }
        __syncthreads();
        short8 af[4], bf8[4];
        #pragma unroll
        for (int m = 0; m < 4; m++) af[m]  = *reinterpret_cast<const short8*>(&As[wm + m * 16 + fr][fc]);
        #pragma unroll
        for (int n = 0; n < 4; n++) bf8[n] = *reinterpret_cast<const short8*>(&Bs[wn + n * 16 + fr][fc]);
        #pragma unroll
        for (int m = 0; m < 4; m++)
            #pragma unroll
            for (int n = 0; n < 4; n++)
                acc[m][n] = __builtin_amdgcn_mfma_f32_16x16x32_bf16(af[m], bf8[n], acc[m][n], 0, 0, 0);
        __syncthreads();
    }

    const int crow0 = bm0 + wm + (lane >> 4) * 4;
    const int ccol0 = bn0 + wn + fr;
    #pragma unroll
    for (int n = 0; n < 4; n++) {
        const int col = ccol0 + n * 16;
        const float bb = bias[col];
        #pragma unroll
        for (int m = 0; m < 4; m++)
            #pragma unroll
            for (int r = 0; r < 4; r++)
                outp[(size_t)(crow0 + m * 16 + r) * DIM + col] =
                    __float2bfloat16(acc[m][n][r] + bb);
    }
}

// ---------------------------------------------------------------------------
// In-place RMSNorm * g + RoPE. (unchanged, verified)
// ---------------------------------------------------------------------------
__global__ __launch_bounds__(256) void rmsnorm_rope(
    __hip_bfloat16* __restrict__ yq, __hip_bfloat16* __restrict__ yk,
    const float* __restrict__ gq, const float* __restrict__ gk,
    const float* __restrict__ freqs)
{
    const int s = blockIdx.x;
    const int z = blockIdx.y;
    __hip_bfloat16* y = z ? yk : yq;
    const float* g = z ? gk : gq;
    const int t = threadIdx.x;

    float xr[3], xi[3];
    float ss = 0.f;
    #pragma unroll
    for (int i = 0; i < 3; i++) {
        const int p = t + i * 256;
        const unsigned int uu = *reinterpret_cast<const unsigned int*>(&y[(size_t)s * DIM + 2 * p]);
        xr[i] = bf2f((unsigned short)(uu & 0xffffu));
        xi[i] = bf2f((unsigned short)(uu >> 16));
        ss += xr[i] * xr[i] + xi[i] * xi[i];
    }
    #pragma unroll
    for (int m = 1; m < 64; m <<= 1) ss += __shfl_xor(ss, m, 64);
    __shared__ float red[4];
    if ((t & 63) == 0) red[t >> 6] = ss;
    __syncthreads();
    const float sum = red[0] + red[1] + red[2] + red[3];
    const float rs = rsqrtf(sum * (1.0f / DIM) + 1e-6f);
    const int f = s >> 8, hh = (s >> 4) & 15, ww = s & 15;
    const float osc = z ? 1.0f : QSCALE;
    #pragma unroll
    for (int i = 0; i < 3; i++) {
        const int p = t + i * 256;
        const int cc = p & 63;
        const int pos = (cc < 22) ? f : (cc < 43) ? hh : ww;
        const float ang = freqs[pos * 64 + cc];
        float sn, cs;
        sincosf(ang, &sn, &cs);
        const float a = xr[i] * rs * g[2 * p];
        const float b = xi[i] * rs * g[2 * p + 1];
        const unsigned int pk = (unsigned int)f2bf((a * cs - b * sn) * osc)
                              | ((unsigned int)f2bf((a * sn + b * cs) * osc) << 16);
        *reinterpret_cast<unsigned int*>(&y[(size_t)s * DIM + 2 * p]) = pk;
    }
}

// ---------------------------------------------------------------------------
// Transpose V. (unchanged, verified)
// ---------------------------------------------------------------------------
__global__ __launch_bounds__(256) void transpose_v(
    const __hip_bfloat16* __restrict__ vrow,
    __hip_bfloat16* __restrict__ vT)
{
    __shared__ __align__(16) short tile[64][72];
    const int s0 = blockIdx.x * 64;
    const int c0 = blockIdx.y * 64;
    const int t = threadIdx.x;
    #pragma unroll
    for (int i = 0; i < 2; i++) {
        const int ch = t + i * 256;
        const int r = ch >> 3, cc = (ch & 7) * 8;
        *reinterpret_cast<int4*>(&tile[r][cc]) =
            *reinterpret_cast<const int4*>(&vrow[(size_t)(s0 + r) * DIM + c0 + cc]);
    }
    __syncthreads();
    #pragma unroll
    for (int i = 0; i < 2; i++) {
        const int ch = t + i * 256;
        const int c = ch & 63, sc = (ch >> 6) * 8;
        unsigned int w0 = (unsigned short)tile[sc + 0][c] | ((unsigned int)(unsigned short)tile[sc + 1][c] << 16);
        unsigned int w1 = (unsigned short)tile[sc + 2][c] | ((unsigned int)(unsigned short)tile[sc + 3][c] << 16);
        unsigned int w2 = (unsigned short)tile[sc + 4][c] | ((unsigned int)(unsigned short)tile[sc + 5][c] << 16);
        unsigned int w3 = (unsigned short)tile[sc + 6][c] | ((unsigned int)(unsigned short)tile[sc + 7][c] << 16);
        int4 val;
        val.x = (int)w0; val.y = (int)w1; val.z = (int)w2; val.w = (int)w3;
        *reinterpret_cast<int4*>(&vT[(size_t)(c0 + c) * SEQ + s0 + sc]) = val;
    }
}

// ---------------------------------------------------------------------------
// Flash attention v8: v7 compute (32x32x16, verified) rebalanced to a
// 768-block grid (= 3 blocks/CU exactly). QBLK=64 (2 waves x 32 q), 128 thr.
// LDS 48KB: K double-buffered (2x16KB), V single (16KB).
// Per iter: [barA] stage V[t] + prefetch K[t+1] -> QK(K[t]) -> softmax ->
// [barB drains V] -> PV.
// ---------------------------------------------------------------------------
__global__ __launch_bounds__(128, 2) void flash_attn(
    const __hip_bfloat16* __restrict__ qb,
    const __hip_bfloat16* __restrict__ kb,
    const __hip_bfloat16* __restrict__ vT,
    const int* __restrict__ seq_lens,
    __hip_bfloat16* __restrict__ attno)
{
    __shared__ __align__(16) short Ks[2][64][128];   // 2 x 16 KB
    __shared__ __align__(16) short Vs[128][64];      // 16 KB
    const int qt = blockIdx.x;
    const int h  = blockIdx.y;
    const int tid = threadIdx.x;
    const int lane = tid & 63;
    const int w = tid >> 6;          // 0/1
    const int q5 = lane & 31;
    const int hi = lane >> 5;
    const int seqlen = seq_lens[0];
    const int swz = (lane & 7) << 4;

    // Q fragments (B-operand): col q = q5, k-rows = hi*8+e of d-slice s
    short8 qf[8];
    const int qrow = qt * 64 + w * 32 + q5;
    #pragma unroll
    for (int s = 0; s < 8; s++)
        qf[s] = *reinterpret_cast<const short8*>(&qb[(size_t)qrow * DIM + h * HD + s * 16 + hi * 8]);

    f32x16 oacc[4] = {};
    float m = -1e30f, l = 0.f;

    // staging geometry (128 threads; wave-chunk = 1024B)
    const int kROW0 = w * 4 + (lane >> 4);                 // 0..7; + i*8
    const int kCOL  = ((lane & 15) ^ kROW0) * 8;           // pre-swizzled col
    const int vROW0 = w * 8 + (lane >> 3);                 // 0..15; + i*16
    const int vCOL  = ((lane & 7) ^ (vROW0 & 7)) * 8;

    // prologue: stage K tile 0 into buffer 0
    #pragma unroll
    for (int i = 0; i < 8; i++)
        async_cp16(&Ks[0][i * 8 + w * 4][0],
                   kb + (size_t)(i * 8 + kROW0) * DIM + h * HD + kCOL);

    for (int t = 0; t < SEQ / 64; t++) {
        const int kbase = t * 64;
        __syncthreads();   // (A) prev reads done; K[t] drained (prev barB / prologue at first barB)

        // stage V[t]; prefetch K[t+1]
        #pragma unroll
        for (int i = 0; i < 8; i++)
            async_cp16(&Vs[i * 16 + vROW0][0],
                       vT + ((size_t)h * HD + i * 16 + vROW0) * SEQ + kbase + vCOL);
        if (t + 1 < SEQ / 64) {
            const int nb = kbase + 64;
            #pragma unroll
            for (int i = 0; i < 8; i++)
                async_cp16(&Ks[(t + 1) & 1][i * 8 + w * 4][0],
                           kb + (size_t)(nb + i * 8 + kROW0) * DIM + h * HD + kCOL);
        }

        const char* Kp = (const char*)&Ks[t & 1][0][0];

        // S^T = K Q^T : D[key 32][q 32], 2 key-blocks x 8 d-slices
        f32x16 sacc[2] = {};
        __builtin_amdgcn_s_setprio(1);
        #pragma unroll
        for (int s = 0; s < 8; s++) {
            #pragma unroll
            for (int kbk = 0; kbk < 2; kbk++) {
                short8 kf = *reinterpret_cast<const short8*>(
                    Kp + (kbk * 32 + q5) * 256 + ((s * 32 + hi * 16) ^ swz));
                sacc[kbk] = __builtin_amdgcn_mfma_f32_32x32x16_bf16(kf, qf[s], sacc[kbk], 0, 0, 0);
            }
        }
        __builtin_amdgcn_s_setprio(0);

        // row max
        float tmax = -1e30f;
        if (kbase + 64 <= seqlen) {
            #pragma unroll
            for (int kbk = 0; kbk < 2; kbk++)
                #pragma unroll
                for (int r = 0; r < 16; r++) tmax = fmaxf(tmax, sacc[kbk][r]);
        } else {
            #pragma unroll
            for (int kbk = 0; kbk < 2; kbk++) {
                #pragma unroll
                for (int r = 0; r < 16; r++) {
                    const int key = kbase + kbk * 32 + (r & 3) + 8 * (r >> 2) + 4 * hi;
                    const float sv = (key < seqlen) ? sacc[kbk][r] : -1e30f;
                    sacc[kbk][r] = sv;
                    tmax = fmaxf(tmax, sv);
                }
            }
        }
        tmax = fmaxf(tmax, __shfl_xor(tmax, 32, 64));

        // defer-max (T13)
        if (!__all(tmax <= m + 8.0f)) {
            const float mn = fmaxf(m, tmax);
            const float alpha = exp2f((m - mn) * LOG2E);
            m = mn;
            l *= alpha;
            #pragma unroll
            for (int cb = 0; cb < 4; cb++)
                #pragma unroll
                for (int r = 0; r < 16; r++) oacc[cb][r] *= alpha;
        }

        // P = exp(S - m); row sum
        float ps = 0.f;
        #pragma unroll
        for (int kbk = 0; kbk < 2; kbk++) {
            #pragma unroll
            for (int r = 0; r < 16; r++) {
                const float p = exp2f((sacc[kbk][r] - m) * LOG2E);
                sacc[kbk][r] = p;
                ps += p;
            }
        }
        ps += __shfl_xor(ps, 32, 64);
        l += ps;

        // pack P
        unsigned int W[2][4][2];
        #pragma unroll
        for (int kbk = 0; kbk < 2; kbk++)
            #pragma unroll
            for (int tq = 0; tq < 4; tq++) {
                W[kbk][tq][0] = (unsigned int)f2bf(sacc[kbk][4 * tq + 0])
                              | ((unsigned int)f2bf(sacc[kbk][4 * tq + 1]) << 16);
                W[kbk][tq][1] = (unsigned int)f2bf(sacc[kbk][4 * tq + 2])
                              | ((unsigned int)f2bf(sacc[kbk][4 * tq + 3]) << 16);
            }

        __syncthreads();   // (B) V[t] (and K[t+1]) staged

        // O^T += V^T P
        const char* Vp = (const char*)&Vs[0][0];
        #pragma unroll
        for (int ks = 0; ks < 4; ks++) {
            const int kbk = ks >> 1;
            const int te = (ks & 1) * 2, to = te + 1;
            const int a0 = (int)W[kbk][te][0], a1 = (int)W[kbk][te][1];
            const int b0 = (int)W[kbk][to][0], b1 = (int)W[kbk][to][1];
            const int xa0 = __shfl_xor(a0, 32, 64);
            const int xa1 = __shfl_xor(a1, 32, 64);
            const int xb0 = __shfl_xor(b0, 32, 64);
            const int xb1 = __shfl_xor(b1, 32, 64);
            int4 pwv;
            pwv.x = hi ? xb0 : a0;
            pwv.y = hi ? xb1 : a1;
            pwv.z = hi ? b0  : xa0;
            pwv.w = hi ? b1  : xa1;
            const short8 pf = __builtin_bit_cast(short8, pwv);
            __builtin_amdgcn_s_setprio(1);
            #pragma unroll
            for (int cb = 0; cb < 4; cb++) {
                short8 vf = *reinterpret_cast<const short8*>(
                    Vp + (cb * 32 + q5) * 128 + ((ks * 32 + hi * 16) ^ swz));
                oacc[cb] = __builtin_amdgcn_mfma_f32_32x32x16_bf16(vf, pf, oacc[cb], 0, 0, 0);
            }
            __builtin_amdgcn_s_setprio(0);
        }
    }

    // epilogue: O = O^T / l, packed 8B stores
    const float inv_l = 1.f / l;
    const size_t obase = (size_t)qrow * DIM + h * HD;
    #pragma unroll
    for (int cb = 0; cb < 4; cb++) {
        #pragma unroll
        for (int tq = 0; tq < 4; tq++) {
            uint2 pko;
            pko.x = (unsigned int)f2bf(oacc[cb][4 * tq + 0] * inv_l)
                  | ((unsigned int)f2bf(oacc[cb][4 * tq + 1] * inv_l) << 16);
            pko.y = (unsigned int)f2bf(oacc[cb][4 * tq + 2] * inv_l)
                  | ((unsigned int)f2bf(oacc[cb][4 * tq + 3] * inv_l) << 16);
            *reinterpret_cast<uint2*>(&attno[obase + cb * 32 + 8 * tq + 4 * hi]) = pko;
        }
    }
}

// ---------------------------------------------------------------------------
// Output GEMM (m97-style staging). (unchanged, verified)
// ---------------------------------------------------------------------------
__global__ __launch_bounds__(256) void gemm_out(
    const __hip_bfloat16* __restrict__ A,
    const __hip_bfloat16* __restrict__ W,
    const float* __restrict__ bias,
    float* __restrict__ outp)
{
    __shared__ __align__(16) short As[128][32];
    __shared__ __align__(16) short Bs[128][32];
    const int bm0 = blockIdx.x * 128;
    const int bn0 = blockIdx.y * 128;
    const int tid = threadIdx.x;
    const int lane = tid & 63;
    const int wid = tid >> 6;
    const int wm = (wid >> 1) * 64;
    const int wn = (wid & 1) * 64;
    const int fr = lane & 15;
    const int fc = (lane >> 4) * 8;
    const int srow = tid >> 2;
    const int scol = (tid & 3) * 8;

    f32x4 acc[4][4] = {};

    for (int kt = 0; kt < DIM; kt += 32) {
        #pragma unroll
        for (int i = 0; i < 2; i++) {
            async_cp16(&As[i * 64 + ((tid >> 6) << 4)][0],
                       A + (size_t)(bm0 + i * 64 + srow) * DIM + kt + scol);
            async_cp16(&Bs[i * 64 + ((tid >> 6) << 4)][0],
                       W + (size_t)(bn0 + i * 64 + srow) * DIM + kt + scol);
        }
        __syncthreads();
        short8 af[4], bf8[4];
        #pragma unroll
        for (int m = 0; m < 4; m++) af[m]  = *reinterpret_cast<const short8*>(&As[wm + m * 16 + fr][fc]);
        #pragma unroll
        for (int n = 0; n < 4; n++) bf8[n] = *reinterpret_cast<const short8*>(&Bs[wn + n * 16 + fr][fc]);
        #pragma unroll
        for (int m = 0; m < 4; m++)
            #pragma unroll
            for (int n = 0; n < 4; n++)
                acc[m][n] = __builtin_amdgcn_mfma_f32_16x16x32_bf16(af[m], bf8[n], acc[m][n], 0, 0, 0);
        __syncthreads();
    }

    const int crow0 = bm0 + wm + (lane >> 4) * 4;
    const int ccol0 = bn0 + wn + fr;
    #pragma unroll
    for (int n = 0; n < 4; n++) {
        const int col = ccol0 + n * 16;
        const float bb = bias[col];
        #pragma unroll
        for (int m = 0; m < 4; m++)
            #pragma unroll
            for (int r = 0; r < 4; r++)
                outp[(size_t)(crow0 + m * 16 + r) * DIM + col] = acc[m][n][r] + bb;
    }
}

// ---------------------------------------------------------------------------
extern "C" void kernel_launch(void* const* d_in, const int* in_sizes, int n_in,
                              void* d_out, int out_size, void* d_ws, size_t ws_size,
                              hipStream_t stream)
{
    const float* x        = (const float*)d_in[0];
    const int*   seq_lens = (const int*)d_in[1];
    const float* freqs    = (const float*)d_in[3];
    const float* wq = (const float*)d_in[4];
    const float* bq = (const float*)d_in[5];
    const float* wk = (const float*)d_in[6];
    const float* bk = (const float*)d_in[7];
    const float* wv = (const float*)d_in[8];
    const float* bv = (const float*)d_in[9];
    const float* wo = (const float*)d_in[10];
    const float* bo = (const float*)d_in[11];
    const float* gq = (const float*)d_in[12];
    const float* gk = (const float*)d_in[13];
    float* out = (float*)d_out;

    // workspace (50,331,648 bytes) + d_out used as early scratch:
    //   yq bf16 [0, 12582912)          (q; dead after flash -> wob aliases)
    //   yk bf16 [12582912, 25165824)
    //   vrow bf16 [25165824, 37748736) (dead after transpose_v; attno aliases)
    //   vT bf16 [37748736, 50331648)   (xb lives here until transpose_v)
    //   wq/wk/wv bf16 -> d_out scratch (until gemm_out writes)
    char* ws = (char*)d_ws;
    __hip_bfloat16* yq    = (__hip_bfloat16*)(ws);
    __hip_bfloat16* yk    = (__hip_bfloat16*)(ws + 12582912);
    __hip_bfloat16* vrow  = (__hip_bfloat16*)(ws + 25165824);
    __hip_bfloat16* vT    = (__hip_bfloat16*)(ws + 37748736);
    __hip_bfloat16* attno = (__hip_bfloat16*)(ws + 25165824);
    __hip_bfloat16* xb    = (__hip_bfloat16*)(ws + 37748736);
    __hip_bfloat16* wob   = (__hip_bfloat16*)(ws);
    __hip_bfloat16* wqb   = (__hip_bfloat16*)d_out;
    __hip_bfloat16* wkb   = wqb + 2359296;
    __hip_bfloat16* wvb   = wkb + 2359296;

    dim3 blk(256);
    convert_bf16<<<dim3(3072), blk, 0, stream>>>(x,  xb,  786432);
    convert_bf16<<<dim3(1152), blk, 0, stream>>>(wq, wqb, 294912);
    convert_bf16<<<dim3(1152), blk, 0, stream>>>(wk, wkb, 294912);
    convert_bf16<<<dim3(1152), blk, 0, stream>>>(wv, wvb, 294912);
    gemm_qkv    <<<dim3(32, 12, 3), blk, 0, stream>>>(xb, wqb, bq, wkb, bk, wvb, bv, yq, yk, vrow);
    rmsnorm_rope<<<dim3(4096, 2),   blk, 0, stream>>>(yq, yk, gq, gk, freqs);
    transpose_v <<<dim3(64, 24),    blk, 0, stream>>>(vrow, vT);
    flash_attn  <<<dim3(64, 12),    dim3(128), 0, stream>>>(yq, yk, vT, seq_lens, attno);
    convert_bf16<<<dim3(1152), blk, 0, stream>>>(wo, wob, 294912);
    gemm_out    <<<dim3(32, 12),    blk, 0, stream>>>(attno, wob, bo, out);
}